// Round 1
// baseline (372.472 us; speedup 1.0000x reference)
//
#include <hip/hip_runtime.h>

#define NB 524288
#define ND 64
#define NH 19
#define NP 10      // padded pair count (20 elems)
#define NBLK 2048  // blocks for ltc_absum and ltc_fused (256 threads each)

typedef float v2f __attribute__((ext_vector_type(2)));

__device__ __forceinline__ v2f splat2(float x) { return (v2f){x, x}; }
__device__ __forceinline__ v2f fma2(v2f a, v2f b, v2f c) {
    return __builtin_elementwise_fma(a, b, c);
}
__device__ __forceinline__ float rfl(float v) {  // readfirstlane (force SGPR)
    union { float f; int i; } a; a.f = v;
    a.i = __builtin_amdgcn_readfirstlane(a.i);
    return a.f;
}

// Padé(5,4) tanh, clamped: max |err| ~1e-3 (at x~3.5), well under tolerance.
__device__ __forceinline__ v2f tanh2(v2f x) {
    v2f x2 = x * x;
    v2f n  = fma2(x2, x2 + splat2(105.f), splat2(945.f));
    v2f d  = fma2(x2, fma2(x2, splat2(15.f), splat2(420.f)), splat2(945.f));
    v2f xn = x * n;
    v2f y  = {xn.x * __builtin_amdgcn_rcpf(d.x), xn.y * __builtin_amdgcn_rcpf(d.y)};
    y = __builtin_elementwise_min(y, splat2(1.f));
    y = __builtin_elementwise_max(y, splat2(-1.f));
    return y;
}

// Setup: pair-transposed weight tables so packed FMAs get contiguous uniform
// float2 (SGPR) loads. W?2[k][t] = (W[2t][k], W[2t+1][k]), pad t=9.y with 0.
extern "C" __global__ void __launch_bounds__(64)
ltc_setup(const float* __restrict__ Wi, const float* __restrict__ bi,
          const float* __restrict__ Wr, const float* __restrict__ Wo,
          const float* __restrict__ bo,
          float2* __restrict__ Wi2, float2* __restrict__ bi2,
          float2* __restrict__ Wr2, float2* __restrict__ Wo2,
          float2* __restrict__ bo2)
{
    for (int i = threadIdx.x; i < NH * NP; i += 64) {
        int k = i / NP, t = i % NP;
        float rx = Wr[(2 * t) * NH + k];
        float ry = (2 * t + 1 < NH) ? Wr[(2 * t + 1) * NH + k] : 0.f;
        Wr2[i] = make_float2(rx, ry);
        float ox = Wo[(2 * t) * NH + k];
        float oy = (2 * t + 1 < NH) ? Wo[(2 * t + 1) * NH + k] : 0.f;
        Wo2[i] = make_float2(ox, oy);
    }
    // Wi2[col*NP + t] = (Wi[2t][col], Wi[2t+1][col]), col = 0..63
    for (int i = threadIdx.x; i < ND * NP; i += 64) {
        int col = i / NP, t = i % NP;
        float ax = Wi[(2 * t) * ND + col];
        float ay = (2 * t + 1 < NH) ? Wi[(2 * t + 1) * ND + col] : 0.f;
        Wi2[i] = make_float2(ax, ay);
    }
    if (threadIdx.x < NP) {
        int t = threadIdx.x;
        bo2[t] = make_float2(bo[2 * t], (2 * t + 1 < NH) ? bo[2 * t + 1] : 0.f);
        bi2[t] = make_float2(bi[2 * t], (2 * t + 1 < NH) ? bi[2 * t + 1] : 0.f);
    }
}

// Kernel 1: pure |x| reduction (also warms L3 with x). 134 MB read, ~22 us.
extern "C" __global__ void __launch_bounds__(256)
ltc_absum(const float* __restrict__ x, float* __restrict__ partials)
{
    __shared__ float red[4];
    const int t = threadIdx.x;
    const float4* xg = (const float4*)x + (size_t)blockIdx.x * 4096;
    float s = 0.f;
#pragma unroll
    for (int i = 0; i < 16; ++i) {
        const float4 v = xg[i * 256 + t];
        s += fabsf(v.x) + fabsf(v.y) + fabsf(v.z) + fabsf(v.w);
    }
#pragma unroll
    for (int off = 32; off > 0; off >>= 1) s += __shfl_down(s, off, 64);
    if ((t & 63) == 0) red[t >> 6] = s;
    __syncthreads();
    if (t == 0) partials[blockIdx.x] = red[0] + red[1] + red[2] + red[3];
}

// Kernel 2: fused mapped-matvec + recurrence + output. No mapped round-trip.
// LDS: 4 waves x [64][34] f32 tile (stride 34 -> b64-aligned, 2-way banks =
// free) = 34816 B -> 4 blocks/CU. VGPR target <=128 (4 waves/SIMD) so all
// state (m2+h2+p2+rr2 ~ 90) stays in arch VGPRs -- no AGPR shuttling.
extern "C" __global__ void __launch_bounds__(256, 4)
ltc_fused(const float* __restrict__ x, const float* __restrict__ partials,
          const v2f* __restrict__ Wi2, const v2f* __restrict__ bi2,
          const v2f* __restrict__ Wr2, const v2f* __restrict__ Wo2,
          const v2f* __restrict__ bo2, const float* __restrict__ tau,
          const float* __restrict__ ta, const int* __restrict__ steps_p,
          float* __restrict__ out)
{
    __shared__ float lds[4 * 64 * 34];  // phase-B tiles; reused for staging
    __shared__ float red[4];
    const int t = threadIdx.x;
    const int l = t & 63, w = t >> 6;
    const int rowbase = blockIdx.x * 256;

    // --- urgency: deterministic re-reduction of the 2048 partials ---
    float ps = 0.f;
#pragma unroll
    for (int i = 0; i < NBLK / 256; ++i) ps += partials[t + 256 * i];
#pragma unroll
    for (int off = 32; off > 0; off >>= 1) ps += __shfl_down(ps, off, 64);
    if ((t & 63) == 0) red[t >> 6] = ps;
    __syncthreads();
    const float total = red[0] + red[1] + red[2] + red[3];
    const float u = rfl(fmaxf(total * (1.f / ((float)NB * (float)ND)), 0.01f));
    const float inv_u = 1.f / u;

    // --- phase B: m2 = x @ Wi^T + bi, packed. Per-wave LDS transpose in two
    // 32-col chunks. Global loads: 8 rows x 128B contiguous per instruction.
    v2f m2[NP];
#pragma unroll
    for (int j = 0; j < NP; ++j) m2[j] = bi2[j];
    {
        float* tw = lds + w * (64 * 34);
        const float4* xg = (const float4*)x + (size_t)(rowbase + w * 64) * 16;
#pragma unroll
        for (int c = 0; c < 2; ++c) {
#pragma unroll
            for (int i = 0; i < 8; ++i) {
                const int flat = i * 64 + l, row = flat >> 3, cq = flat & 7;
                const float4 v = xg[row * 16 + c * 8 + cq];
                *(float2*)&tw[row * 34 + cq * 4]     = make_float2(v.x, v.y);
                *(float2*)&tw[row * 34 + cq * 4 + 2] = make_float2(v.z, v.w);
            }
            __syncthreads();  // cheap wave-sync; guards write->read ordering
#pragma unroll
            for (int q = 0; q < 16; ++q) {
                const float2 v = *(const float2*)&tw[l * 34 + 2 * q];
                const int col = c * 32 + 2 * q;
                const v2f vx = splat2(v.x), vy = splat2(v.y);
                const v2f* wc0 = Wi2 + (size_t)col * NP;
                const v2f* wc1 = Wi2 + (size_t)(col + 1) * NP;
#pragma unroll
                for (int j = 0; j < NP; ++j) m2[j] = fma2(vx, wc0[j], m2[j]);
#pragma unroll
                for (int j = 0; j < NP; ++j) m2[j] = fma2(vy, wc1[j], m2[j]);
            }
            __syncthreads();  // reads done before next chunk overwrites tile
        }
    }

    // --- rr2 (computed late to keep phase-B register pressure down) ---
    v2f rr2[NP];
#pragma unroll
    for (int j = 0; j < NP; ++j) {
        int j0 = 2 * j, j1 = (2 * j + 1 < NH) ? 2 * j + 1 : 2 * j;
        float t0 = fminf(10.f, fmaxf(0.01f, tau[j0] * (1.f - ta[j0]) + ta[j0] * inv_u));
        float t1 = fminf(10.f, fmaxf(0.01f, tau[j1] * (1.f - ta[j1]) + ta[j1] * inv_u));
        rr2[j] = (v2f){0.01f / t0, 0.01f / t1};
    }

    v2f h2[NP];
#pragma unroll
    for (int j = 0; j < NP; ++j) h2[j] = splat2(0.f);

    // --- recurrence: h <- h + (dt/tau)*(tanh(m + h@Wr^T) - h) ---
    const int steps = *steps_p;
    const v2f* wr = Wr2;
    for (int s = 0; s < steps; ++s) {
        v2f p2[NP];
        {
            const v2f hb = splat2(h2[0].x);
#pragma unroll
            for (int j = 0; j < NP; ++j) p2[j] = fma2(hb, wr[j], m2[j]);
        }
#pragma unroll
        for (int k = 1; k < NH; ++k) {
            const float hk = (k & 1) ? h2[k >> 1].y : h2[k >> 1].x;
            const v2f hb = splat2(hk);
            const v2f* wrow = wr + k * NP;
#pragma unroll
            for (int j = 0; j < NP; ++j) p2[j] = fma2(hb, wrow[j], p2[j]);
        }
#pragma unroll
        for (int j = 0; j < NP; ++j) p2[j] = tanh2(p2[j]);  // reuse p2 as act
#pragma unroll
        for (int j = 0; j < NP; ++j) h2[j] = fma2(rr2[j], p2[j] - h2[j], h2[j]);
    }

    // --- epilogue: o = h @ Wo^T + bo, stage via LDS, float4 stores ---
    const v2f* wo = Wo2;
    v2f o2[NP];
    {
        const v2f hb = splat2(h2[0].x);
#pragma unroll
        for (int j = 0; j < NP; ++j) o2[j] = fma2(hb, wo[j], bo2[j]);
    }
#pragma unroll
    for (int k = 1; k < NH; ++k) {
        const float hk = (k & 1) ? h2[k >> 1].y : h2[k >> 1].x;
        const v2f hb = splat2(hk);
        const v2f* worow = wo + k * NP;
#pragma unroll
        for (int j = 0; j < NP; ++j) o2[j] = fma2(hb, worow[j], o2[j]);
    }
    float* st = lds;  // reuse tile LDS: [256][19] staging (19456 B)
    __syncthreads();
#pragma unroll
    for (int j = 0; j < NH; ++j)
        st[t * NH + j] = (j & 1) ? o2[j >> 1].y : o2[j >> 1].x;
    __syncthreads();
    {
        const float4* s4 = (const float4*)st;
        float4* o4 = (float4*)(out + (size_t)blockIdx.x * 256 * NH);
#pragma unroll
        for (int i = 0; i < 4; ++i) o4[t + i * 256] = s4[t + i * 256];
        if (t + 1024 < 1216) o4[t + 1024] = s4[t + 1024];
    }
    __syncthreads();
#pragma unroll
    for (int j = 0; j < NH; ++j)
        st[t * NH + j] = (j & 1) ? h2[j >> 1].y : h2[j >> 1].x;
    __syncthreads();
    {
        const float4* s4 = (const float4*)st;
        float4* o4 = (float4*)(out + (size_t)NB * NH + (size_t)blockIdx.x * 256 * NH);
#pragma unroll
        for (int i = 0; i < 4; ++i) o4[t + i * 256] = s4[t + i * 256];
        if (t + 1024 < 1216) o4[t + 1024] = s4[t + 1024];
    }
}

extern "C" void kernel_launch(void* const* d_in, const int* in_sizes, int n_in,
                              void* d_out, int out_size, void* d_ws, size_t ws_size,
                              hipStream_t stream)
{
    const float* x   = (const float*)d_in[0];
    const float* Wi  = (const float*)d_in[1];
    const float* bi  = (const float*)d_in[2];
    const float* Wr  = (const float*)d_in[3];
    const float* Wo  = (const float*)d_in[4];
    const float* bo  = (const float*)d_in[5];
    const float* tau = (const float*)d_in[6];
    const float* ta  = (const float*)d_in[7];
    const int* steps = (const int*)d_in[8];
    float* out = (float*)d_out;

    // ws layout (all fully overwritten every call)
    float*  partials = (float*)d_ws;                    // 8192 B
    float2* Wr2 = (float2*)((char*)d_ws + 8192);        // 1520 B
    float2* Wo2 = (float2*)((char*)d_ws + 9728);        // 1520 B
    float2* bo2 = (float2*)((char*)d_ws + 11264);       // 80 B
    float2* bi2 = (float2*)((char*)d_ws + 11360);       // 80 B
    float2* Wi2 = (float2*)((char*)d_ws + 11456);       // 5120 B

    ltc_setup<<<1, 64, 0, stream>>>(Wi, bi, Wr, Wo, bo, Wi2, bi2, Wr2, Wo2, bo2);
    ltc_absum<<<NBLK, 256, 0, stream>>>(x, partials);
    ltc_fused<<<NBLK, 256, 0, stream>>>(x, partials, (const v2f*)Wi2,
                                        (const v2f*)bi2, (const v2f*)Wr2,
                                        (const v2f*)Wo2, (const v2f*)bo2,
                                        tau, ta, steps, out);
}